// Round 9
// baseline (39.831 us; speedup 1.0000x reference)
//
#include <hip/hip_runtime.h>

typedef unsigned short ushort_t;
typedef unsigned int uint_t;
typedef __attribute__((ext_vector_type(8))) short short8;
typedef __attribute__((ext_vector_type(4))) float f32x4;

#define IN_DIM 256
#define OUT_DIM 256
#define BATCH 512
#define NSPL 11                  // 11 bases
#define KSLOT 12                 // + silu/residual slot
#define CHUNK_I 32               // inputs per K-chunk
#define KC (CHUNK_I * KSLOT)     // 384 K-slots per chunk
#define LSTRIDE (KC + 8)         // 392 elems = 784B row stride (=16 mod 128B)
#define NCHUNK 8

__device__ __forceinline__ ushort_t f2bf(float f) {
  union { float f; uint_t i; } c; c.f = f;
  uint_t u = c.i;
  u = u + 0x7FFFu + ((u >> 16) & 1u);   // RNE
  return (ushort_t)(u >> 16);
}

// closed-form cubic B-spline cell -> 6 packed dwords (12 bf16 slots)
__device__ __forceinline__ void packA(float xf, uint_t o6[6]) {
  const float t = (xf + 1.75f) * 4.0f;
  const float fJ = floorf(t);
  const int J = (int)fJ;
  const float u = t - fJ;
  const bool inr = (J >= 0) && (J <= 13);

  const float u2 = u * u, u3 = u2 * u, um = 1.0f - u;
  const float n0 = um * um * um * (1.0f / 6.0f);
  const float n1 = 0.5f * u3 - u2 + (4.0f / 6.0f);
  const float n2 = -0.5f * u3 + 0.5f * u2 + 0.5f * u + (1.0f / 6.0f);
  const float n3 = u3 * (1.0f / 6.0f);
  const float silu = xf / (1.0f + __expf(-xf));

  ushort_t v[KSLOT];
#pragma unroll
  for (int g = 0; g < NSPL; ++g) {
    const int k = g - J + 3;
    float val = 0.0f;
    if (inr) {
      if (k == 0) val = n0;
      else if (k == 1) val = n1;
      else if (k == 2) val = n2;
      else if (k == 3) val = n3;
    }
    v[g] = f2bf(val);
  }
  v[11] = f2bf(silu);
#pragma unroll
  for (int j = 0; j < 6; ++j) o6[j] = (uint_t)v[2 * j] | ((uint_t)v[2 * j + 1] << 16);
}

__device__ __forceinline__ void packW(const float* cf, float us, float r, uint_t o6[6]) {
  ushort_t v[KSLOT];
#pragma unroll
  for (int g = 0; g < NSPL; ++g) v[g] = f2bf(us * cf[g]);
  v[11] = f2bf(r);
#pragma unroll
  for (int j = 0; j < 6; ++j) o6[j] = (uint_t)v[2 * j] | ((uint_t)v[2 * j + 1] << 16);
}

// ONE kernel, 512 blocks x 256 threads, zero cross-block sync.
// Block = 16x16 output tile; per K-chunk (32 inputs): double-buffered LDS build
// (loads for c+1 hoisted before MFMA of c), 1 barrier/chunk, split-K MFMA.
__global__ __launch_bounds__(256, 2) void fused(const float* __restrict__ x,
                                                const float* __restrict__ coef,
                                                const float* __restrict__ rw,
                                                const float* __restrict__ uw,
                                                float* __restrict__ out) {
  __shared__ __attribute__((aligned(16))) ushort_t As[2][16 * LSTRIDE];
  __shared__ __attribute__((aligned(16))) ushort_t Ws[2][16 * LSTRIDE];
  __shared__ f32x4 red[3][64];

  const int tid = threadIdx.x;
  const int lane = tid & 63;
  const int w = tid >> 6;                      // wave 0..3 = K-slice owner
  const int B = blockIdx.x;
  // XCD-aware swizzle: XCD r (B%8) serves N-tiles {2r,2r+1} -> coef slice L2-captive
  const int mt = B >> 4;                       // 0..31
  const int nt = ((B & 7) << 1) | ((B >> 3) & 1); // 0..15
  const int b0 = mt * 16, o0 = nt * 16;
  const int mn = lane & 15;
  const int klane = (lane >> 4) * 8;

  const int row = tid >> 4;                    // 0..15 (tile row this thread builds)
  const int i0 = tid & 15;                     // cells (row,i0) and (row,i0+16)

  // staged registers for next chunk
  float xa0, xa1;
  float cf0[11], cf1[11];
  float us0, us1, r0, r1;

#define LOAD_CHUNK(C)                                                      \
  {                                                                        \
    const int ib = (C) * CHUNK_I;                                          \
    xa0 = x[(b0 + row) * IN_DIM + ib + i0];                                \
    xa1 = x[(b0 + row) * IN_DIM + ib + i0 + 16];                           \
    const size_t oiA = (size_t)(o0 + row) * IN_DIM + ib + i0;              \
    const size_t oiB = oiA + 16;                                           \
    _Pragma("unroll")                                                      \
    for (int g = 0; g < NSPL; ++g) {                                       \
      cf0[g] = coef[oiA * NSPL + g];                                       \
      cf1[g] = coef[oiB * NSPL + g];                                       \
    }                                                                      \
    us0 = uw[oiA]; us1 = uw[oiB];                                          \
    r0 = rw[oiA];  r1 = rw[oiB];                                           \
  }

#define STORE_CHUNK(BUF)                                                   \
  {                                                                        \
    uint_t p[6];                                                           \
    packA(xa0, p);                                                         \
    uint_t* dA0 = (uint_t*)&As[BUF][row * LSTRIDE + i0 * KSLOT];           \
    _Pragma("unroll") for (int j = 0; j < 6; ++j) dA0[j] = p[j];           \
    packA(xa1, p);                                                         \
    uint_t* dA1 = (uint_t*)&As[BUF][row * LSTRIDE + (i0 + 16) * KSLOT];    \
    _Pragma("unroll") for (int j = 0; j < 6; ++j) dA1[j] = p[j];           \
    packW(cf0, us0, r0, p);                                                \
    uint_t* dW0 = (uint_t*)&Ws[BUF][row * LSTRIDE + i0 * KSLOT];           \
    _Pragma("unroll") for (int j = 0; j < 6; ++j) dW0[j] = p[j];           \
    packW(cf1, us1, r1, p);                                                \
    uint_t* dW1 = (uint_t*)&Ws[BUF][row * LSTRIDE + (i0 + 16) * KSLOT];    \
    _Pragma("unroll") for (int j = 0; j < 6; ++j) dW1[j] = p[j];           \
  }

  // prologue: chunk 0
  LOAD_CHUNK(0)
  STORE_CHUNK(0)
  __syncthreads();

  f32x4 acc = {0.f, 0.f, 0.f, 0.f};

  for (int c = 0; c < NCHUNK; ++c) {
    const int cur = c & 1;

    if (c + 1 < NCHUNK) { LOAD_CHUNK(c + 1) }          // issue next-chunk loads FIRST
    __builtin_amdgcn_sched_barrier(0);                 // keep them issued here

    // MFMA: wave w owns K-slice [w*96, w*96+96) of current chunk
#pragma unroll
    for (int s = 0; s < 3; ++s) {
      const int k = w * 96 + s * 32 + klane;
      short8 af  = *(const short8*)&As[cur][mn * LSTRIDE + k];
      short8 bfr = *(const short8*)&Ws[cur][mn * LSTRIDE + k];
      acc = __builtin_amdgcn_mfma_f32_16x16x32_bf16(af, bfr, acc, 0, 0, 0);
    }

    if (c + 1 < NCHUNK) { STORE_CHUNK(cur ^ 1) }       // build next chunk (other buffer)
    __syncthreads();                                   // one barrier per chunk
  }

  // cross-wave split-K reduce, then write
  if (w > 0) red[w - 1][lane] = acc;
  __syncthreads();

  if (w == 0) {
    const f32x4 q0 = red[0][lane];
    const f32x4 q1 = red[1][lane];
    const f32x4 q2 = red[2][lane];
#pragma unroll
    for (int q = 0; q < 4; ++q) acc[q] += q0[q] + q1[q] + q2[q];

    // C/D layout (HW-verified): col = lane&15, row = (lane>>4)*4 + reg
    const int col = o0 + mn;
    const int rbase = b0 + (lane >> 4) * 4;
#pragma unroll
    for (int r = 0; r < 4; ++r) {
      out[(size_t)(rbase + r) * OUT_DIM + col] = acc[r];
    }
  }
}

extern "C" void kernel_launch(void* const* d_in, const int* in_sizes, int n_in,
                              void* d_out, int out_size, void* d_ws, size_t ws_size,
                              hipStream_t stream) {
  const float* x    = (const float*)d_in[0];
  const float* coef = (const float*)d_in[1];
  const float* rw   = (const float*)d_in[2];
  const float* uw   = (const float*)d_in[3];
  float* out = (float*)d_out;

  fused<<<512, 256, 0, stream>>>(x, coef, rw, uw, out);
}

// Round 10
// 24.617 us; speedup vs baseline: 1.6181x; 1.6181x over previous
//
#include <hip/hip_runtime.h>
#include <hip/hip_bf16.h>

typedef unsigned short ushort_t;
typedef unsigned int uint_t;
typedef __attribute__((ext_vector_type(8))) short short8;
typedef __attribute__((ext_vector_type(4))) float f32x4;

#define IN_DIM 256
#define OUT_DIM 256
#define NSPL 11                  // 11 bases
#define KSLOT 12                 // + silu/residual slot
#define CHUNK_I 32               // inputs per K-chunk
#define KC (CHUNK_I * KSLOT)     // 384 K-slots per chunk
#define LSTRIDE (KC + 8)         // 392 ushorts = 784B row stride (=16 mod 128B)
#define NCHUNK 8
#define RAWS 177                 // raw coef row: 176 dwords (352 bf16) + 1 pad

__device__ __forceinline__ uint_t pk2(float lo, float hi) {
  __hip_bfloat162 h = __float22bfloat162_rn(make_float2(lo, hi));  // v_cvt_pk_bf16_f32, RNE
  union { __hip_bfloat162 h2; uint_t u; } c; c.h2 = h;
  return c.u;
}
__device__ __forceinline__ float bits2f(uint_t b) {
  union { uint_t u; float f; } c; c.u = b; return c.f;
}

// closed-form cubic B-spline (uniform grid) + silu slot -> 6 packed dwords
__device__ __forceinline__ void packA(float xf, uint_t o6[6]) {
  const float t = (xf + 1.75f) * 4.0f;
  const float fJ = floorf(t);
  const int J = (int)fJ;
  const float u = t - fJ;
  const float u2 = u * u, u3 = u2 * u, um = 1.0f - u;
  const float n0 = um * um * um * (1.0f / 6.0f);                          // basis J-3
  const float n1 = 0.5f * u3 - u2 + (4.0f / 6.0f);                        // basis J-2
  const float n2 = -0.5f * u3 + 0.5f * u2 + 0.5f * u + (1.0f / 6.0f);     // basis J-1
  const float n3 = u3 * (1.0f / 6.0f);                                    // basis J
  const float silu = xf / (1.0f + __expf(-xf));

  float v[12];
#pragma unroll
  for (int g = 0; g < 11; ++g) {
    float val = 0.0f;
    val = (J == g + 3) ? n0 : val;
    val = (J == g + 2) ? n1 : val;
    val = (J == g + 1) ? n2 : val;
    val = (J == g    ) ? n3 : val;
    v[g] = val;
  }
  v[11] = silu;
#pragma unroll
  for (int j = 0; j < 6; ++j) o6[j] = pk2(v[2 * j], v[2 * j + 1]);
}

// W row-cell from LDS-staged bf16 coef: unpack 11 elems (static indices), *us, +r slot
__device__ __forceinline__ void packW(const uint_t* rrow, int i, float us, float r,
                                      uint_t o6[6]) {
  const int dbase = (NSPL * i) >> 1;
  const bool off = (i & 1) != 0;            // parity of 11*i == parity of i
  const uint_t u0 = rrow[dbase + 0], u1 = rrow[dbase + 1], u2 = rrow[dbase + 2];
  const uint_t u3 = rrow[dbase + 3], u4 = rrow[dbase + 4], u5 = rrow[dbase + 5];
  const float lo0 = bits2f(u0 << 16), hi0 = bits2f(u0 & 0xffff0000u);
  const float lo1 = bits2f(u1 << 16), hi1 = bits2f(u1 & 0xffff0000u);
  const float lo2 = bits2f(u2 << 16), hi2 = bits2f(u2 & 0xffff0000u);
  const float lo3 = bits2f(u3 << 16), hi3 = bits2f(u3 & 0xffff0000u);
  const float lo4 = bits2f(u4 << 16), hi4 = bits2f(u4 & 0xffff0000u);
  const float lo5 = bits2f(u5 << 16), hi5 = bits2f(u5 & 0xffff0000u);
  float c[11];
  c[0] = off ? hi0 : lo0;  c[1] = off ? lo1 : hi0;  c[2]  = off ? hi1 : lo1;
  c[3] = off ? lo2 : hi1;  c[4] = off ? hi2 : lo2;  c[5]  = off ? lo3 : hi2;
  c[6] = off ? hi3 : lo3;  c[7] = off ? lo4 : hi3;  c[8]  = off ? hi4 : lo4;
  c[9] = off ? lo5 : hi4;  c[10] = off ? hi5 : lo5;
  o6[0] = pk2(us * c[0], us * c[1]);
  o6[1] = pk2(us * c[2], us * c[3]);
  o6[2] = pk2(us * c[4], us * c[5]);
  o6[3] = pk2(us * c[6], us * c[7]);
  o6[4] = pk2(us * c[8], us * c[9]);
  o6[5] = pk2(us * c[10], r);
}

__device__ __forceinline__ void writeT(ushort_t* dst, const uint_t* p) {
  uint_t* d = (uint_t*)dst;
#pragma unroll
  for (int j = 0; j < 6; ++j) d[j] = p[j];
}

// ONE kernel, 512 blocks x 256 threads, zero cross-block sync.
// Per chunk: coalesced float2 coef loads -> regs -> bf16 rawc LDS (the transpose
// medium) -> pack A/W into double-buffered MFMA tiles; loads for c+1 issue
// before the MFMA of c.
__global__ __launch_bounds__(256, 2) void fused(const float* __restrict__ x,
                                                const float* __restrict__ coef,
                                                const float* __restrict__ rw,
                                                const float* __restrict__ uw,
                                                float* __restrict__ out) {
  __shared__ __attribute__((aligned(16))) ushort_t As[2][16 * LSTRIDE];
  __shared__ __attribute__((aligned(16))) ushort_t Ws[2][16 * LSTRIDE];
  __shared__ __attribute__((aligned(16))) uint_t rawc[16][RAWS];   // reused as `red` at end

  const int tid = threadIdx.x;
  const int lane = tid & 63;
  const int w = tid >> 6;                          // wave 0..3 = K-slice owner
  const int B = blockIdx.x;
  const int mt = B >> 4;                           // 0..31
  const int nt = ((B & 7) << 1) | ((B >> 3) & 1);  // XCD-aware: XCD r owns N-tiles {2r,2r+1}
  const int b0 = mt * 16, o0 = nt * 16;
  const int mn = lane & 15;
  const int klane = (lane >> 4) * 8;

  const int row = tid >> 4;                        // 0..15: tile row this thread builds
  const int i0 = tid & 15;                         // cells (row,i0), (row,i0+16)

  // staged registers for one chunk
  float2 cf[11];
  float xa0, xa1, us0, us1, rr0, rr1;

#define LOADC(C)                                                              \
  {                                                                           \
    const int ib = (C) * CHUNK_I;                                             \
    xa0 = x[(b0 + row) * IN_DIM + ib + i0];                                   \
    xa1 = x[(b0 + row) * IN_DIM + ib + i0 + 16];                              \
    const int orow = o0 + row;                                                \
    us0 = uw[orow * IN_DIM + ib + i0];                                        \
    us1 = uw[orow * IN_DIM + ib + i0 + 16];                                   \
    rr0 = rw[orow * IN_DIM + ib + i0];                                        \
    rr1 = rw[orow * IN_DIM + ib + i0 + 16];                                   \
    const float2* csrc = (const float2*)(coef + ((size_t)orow * IN_DIM + ib) * NSPL); \
    _Pragma("unroll")                                                         \
    for (int j = 0; j < 11; ++j) cf[j] = csrc[i0 + j * 16];  /* 128B/16 lanes */ \
  }

#define CVTSTORE                                                              \
  {                                                                           \
    _Pragma("unroll")                                                         \
    for (int j = 0; j < 11; ++j)                                              \
      rawc[row][i0 + j * 16] = pk2(cf[j].x, cf[j].y);                         \
  }

#define PACK(BUF)                                                             \
  {                                                                           \
    uint_t p6[6];                                                             \
    packA(xa0, p6); writeT(&As[BUF][row * LSTRIDE + i0 * KSLOT], p6);         \
    packA(xa1, p6); writeT(&As[BUF][row * LSTRIDE + (i0 + 16) * KSLOT], p6);  \
    packW(&rawc[row][0], i0, us0, rr0, p6);                                   \
    writeT(&Ws[BUF][row * LSTRIDE + i0 * KSLOT], p6);                         \
    packW(&rawc[row][0], i0 + 16, us1, rr1, p6);                              \
    writeT(&Ws[BUF][row * LSTRIDE + (i0 + 16) * KSLOT], p6);                  \
  }

  f32x4 acc = {0.f, 0.f, 0.f, 0.f};

  // prologue: chunk 0
  LOADC(0)
  CVTSTORE
  __syncthreads();
  PACK(0)
  __syncthreads();

  for (int c = 0; c < NCHUNK; ++c) {
    const int cur = c & 1;

    if (c + 1 < NCHUNK) { LOADC(c + 1) }       // issue next chunk's (coalesced) loads
    __builtin_amdgcn_sched_barrier(0);         // keep them issued before MFMA

    // MFMA: wave w owns K-slice [w*96, w*96+96) of current chunk
#pragma unroll
    for (int s = 0; s < 3; ++s) {
      const int k = w * 96 + s * 32 + klane;
      short8 af  = *(const short8*)&As[cur][mn * LSTRIDE + k];
      short8 bfr = *(const short8*)&Ws[cur][mn * LSTRIDE + k];
      acc = __builtin_amdgcn_mfma_f32_16x16x32_bf16(af, bfr, acc, 0, 0, 0);
    }

    if (c + 1 < NCHUNK) {
      CVTSTORE                                 // waits loads; rawc free (read last chunk, barrier passed)
      __syncthreads();                         // rawc visible
      PACK(cur ^ 1)                            // build next chunk into other buffer
    }
    __syncthreads();
  }

  // cross-wave split-K reduce (red overlays the now-dead rawc), then write
  f32x4* red = (f32x4*)&rawc[0][0];
  if (w > 0) red[(w - 1) * 64 + lane] = acc;
  __syncthreads();

  if (w == 0) {
    const f32x4 q0 = red[lane];
    const f32x4 q1 = red[64 + lane];
    const f32x4 q2 = red[128 + lane];
#pragma unroll
    for (int q = 0; q < 4; ++q) acc[q] += q0[q] + q1[q] + q2[q];

    // C/D layout (HW-verified): col = lane&15, row = (lane>>4)*4 + reg
    const int col = o0 + mn;
    const int rbase = b0 + (lane >> 4) * 4;
#pragma unroll
    for (int r = 0; r < 4; ++r) {
      out[(size_t)(rbase + r) * OUT_DIM + col] = acc[r];
    }
  }
}

extern "C" void kernel_launch(void* const* d_in, const int* in_sizes, int n_in,
                              void* d_out, int out_size, void* d_ws, size_t ws_size,
                              hipStream_t stream) {
  const float* x    = (const float*)d_in[0];
  const float* coef = (const float*)d_in[1];
  const float* rw   = (const float*)d_in[2];
  const float* uw   = (const float*)d_in[3];
  float* out = (float*)d_out;

  fused<<<512, 256, 0, stream>>>(x, coef, rw, uw, out);
}

// Round 11
// 21.853 us; speedup vs baseline: 1.8227x; 1.1265x over previous
//
#include <hip/hip_runtime.h>
#include <hip/hip_bf16.h>

typedef unsigned short ushort_t;
typedef unsigned int uint_t;
typedef __attribute__((ext_vector_type(8))) short short8;
typedef __attribute__((ext_vector_type(4))) float f32x4;

#define IN_DIM 256
#define OUT_DIM 256
#define NSPL 11                  // 11 bases
#define KSLOT 12                 // + silu/residual slot
#define CHUNK_I 32               // inputs per K-chunk
#define KC (CHUNK_I * KSLOT)     // 384 K-slots per chunk
#define LSTRIDE (KC + 8)         // 392 ushorts = 784B row stride; slots KC..KC+7 = pad/dump
#define NCHUNK 8
#define RAWS 177                 // raw coef row: 176 dwords (352 bf16) + 1 pad

__device__ __forceinline__ uint_t pk2(float lo, float hi) {
  __hip_bfloat162 h = __float22bfloat162_rn(make_float2(lo, hi));  // v_cvt_pk_bf16_f32, RNE
  union { __hip_bfloat162 h2; uint_t u; } c; c.h2 = h;
  return c.u;
}
__device__ __forceinline__ float bits2f(uint_t b) {
  union { uint_t u; float f; } c; c.u = b; return c.f;
}

// A-cell: closed-form cubic B-spline; placement via LDS scatter (address path),
// not select chains (VALU path). OOB slots redirect to the row's pad region.
__device__ __forceinline__ void packA_scatter(ushort_t* cb, ushort_t* dump, float xf) {
  const float t = (xf + 1.75f) * 4.0f;
  const float fJ = floorf(t);
  const int J = (int)fJ;
  const float u = t - fJ;
  const float u2 = u * u, u3 = u2 * u, um = 1.0f - u;
  const float n0 = um * um * um * (1.0f / 6.0f);                        // slot J-3
  const float n1 = 0.5f * u3 - u2 + (4.0f / 6.0f);                      // slot J-2
  const float n2 = -0.5f * u3 + 0.5f * u2 + 0.5f * u + (1.0f / 6.0f);   // slot J-1
  const float n3 = u3 * (1.0f / 6.0f);                                  // slot J
  const float silu = xf / (1.0f + __expf(-xf));

  // zero the 12-slot cell (8B-aligned; compiler merges to 3x ds_write_b64)
#pragma unroll
  for (int s = 0; s < 12; ++s) cb[s] = 0;

  const uint_t p01 = pk2(n0, n1);
  const uint_t p23 = pk2(n2, n3);
  const uint_t psl = pk2(silu, silu);

  const int base = J - 3;
  ushort_t* w0 = ((unsigned)(base + 0) <= 10u) ? (cb + base + 0) : (dump + 0);
  ushort_t* w1 = ((unsigned)(base + 1) <= 10u) ? (cb + base + 1) : (dump + 1);
  ushort_t* w2 = ((unsigned)(base + 2) <= 10u) ? (cb + base + 2) : (dump + 2);
  ushort_t* w3 = ((unsigned)(base + 3) <= 10u) ? (cb + base + 3) : (dump + 3);
  *w0 = (ushort_t)p01;
  *w1 = (ushort_t)(p01 >> 16);   // ds_write_b16_d16_hi
  *w2 = (ushort_t)p23;
  *w3 = (ushort_t)(p23 >> 16);
  cb[11] = (ushort_t)psl;
}

// W row-cell from LDS-staged bf16 coef: unpack 11 elems (parity-static), *us, +r slot
__device__ __forceinline__ void packW(const uint_t* rrow, int i, float us, float r,
                                      uint_t o6[6]) {
  const int dbase = (NSPL * i) >> 1;
  const bool off = (i & 1) != 0;            // parity of 11*i == parity of i
  const uint_t u0 = rrow[dbase + 0], u1 = rrow[dbase + 1], u2 = rrow[dbase + 2];
  const uint_t u3 = rrow[dbase + 3], u4 = rrow[dbase + 4], u5 = rrow[dbase + 5];
  const float lo0 = bits2f(u0 << 16), hi0 = bits2f(u0 & 0xffff0000u);
  const float lo1 = bits2f(u1 << 16), hi1 = bits2f(u1 & 0xffff0000u);
  const float lo2 = bits2f(u2 << 16), hi2 = bits2f(u2 & 0xffff0000u);
  const float lo3 = bits2f(u3 << 16), hi3 = bits2f(u3 & 0xffff0000u);
  const float lo4 = bits2f(u4 << 16), hi4 = bits2f(u4 & 0xffff0000u);
  const float lo5 = bits2f(u5 << 16), hi5 = bits2f(u5 & 0xffff0000u);
  float c[11];
  c[0] = off ? hi0 : lo0;  c[1] = off ? lo1 : hi0;  c[2]  = off ? hi1 : lo1;
  c[3] = off ? lo2 : hi1;  c[4] = off ? hi2 : lo2;  c[5]  = off ? lo3 : hi2;
  c[6] = off ? hi3 : lo3;  c[7] = off ? lo4 : hi3;  c[8]  = off ? hi4 : lo4;
  c[9] = off ? lo5 : hi4;  c[10] = off ? hi5 : lo5;
  o6[0] = pk2(us * c[0], us * c[1]);
  o6[1] = pk2(us * c[2], us * c[3]);
  o6[2] = pk2(us * c[4], us * c[5]);
  o6[3] = pk2(us * c[6], us * c[7]);
  o6[4] = pk2(us * c[8], us * c[9]);
  o6[5] = pk2(us * c[10], r);
}

__device__ __forceinline__ void writeT(ushort_t* dst, const uint_t* p) {
  uint_t* d = (uint_t*)dst;
#pragma unroll
  for (int j = 0; j < 6; ++j) d[j] = p[j];
}

// ONE kernel, 512 blocks x 256 threads, zero cross-block sync.
// Per chunk: coalesced float2 coef loads -> regs -> bf16 rawc LDS -> pack A (LDS
// scatter) / W (parity unpack) into double-buffered MFMA tiles; loads for c+1
// issue before the MFMA of c.
__global__ __launch_bounds__(256, 2) void fused(const float* __restrict__ x,
                                                const float* __restrict__ coef,
                                                const float* __restrict__ rw,
                                                const float* __restrict__ uw,
                                                float* __restrict__ out) {
  __shared__ __attribute__((aligned(16))) ushort_t As[2][16 * LSTRIDE];
  __shared__ __attribute__((aligned(16))) ushort_t Ws[2][16 * LSTRIDE];
  __shared__ __attribute__((aligned(16))) uint_t rawc[16][RAWS];   // reused as `red` at end

  const int tid = threadIdx.x;
  const int lane = tid & 63;
  const int w = tid >> 6;                          // wave 0..3 = K-slice owner
  const int B = blockIdx.x;
  const int mt = B >> 4;                           // 0..31
  const int nt = ((B & 7) << 1) | ((B >> 3) & 1);  // XCD-aware: XCD r owns N-tiles {2r,2r+1}
  const int b0 = mt * 16, o0 = nt * 16;
  const int mn = lane & 15;
  const int klane = (lane >> 4) * 8;

  const int row = tid >> 4;                        // 0..15: tile row this thread builds
  const int i0 = tid & 15;                         // cells (row,i0), (row,i0+16)

  // staged registers for one chunk
  float2 cf[11];
  float xa0, xa1, us0, us1, rr0, rr1;

#define LOADC(C)                                                              \
  {                                                                           \
    const int ib = (C) * CHUNK_I;                                             \
    xa0 = x[(b0 + row) * IN_DIM + ib + i0];                                   \
    xa1 = x[(b0 + row) * IN_DIM + ib + i0 + 16];                              \
    const int orow = o0 + row;                                                \
    us0 = uw[orow * IN_DIM + ib + i0];                                        \
    us1 = uw[orow * IN_DIM + ib + i0 + 16];                                   \
    rr0 = rw[orow * IN_DIM + ib + i0];                                        \
    rr1 = rw[orow * IN_DIM + ib + i0 + 16];                                   \
    const float2* csrc = (const float2*)(coef + ((size_t)orow * IN_DIM + ib) * NSPL); \
    _Pragma("unroll")                                                         \
    for (int j = 0; j < 11; ++j) cf[j] = csrc[i0 + j * 16];  /* 128B/16 lanes */ \
  }

#define CVTSTORE                                                              \
  {                                                                           \
    _Pragma("unroll")                                                         \
    for (int j = 0; j < 11; ++j)                                              \
      rawc[row][i0 + j * 16] = pk2(cf[j].x, cf[j].y);                         \
  }

#define PACK(BUF)                                                             \
  {                                                                           \
    ushort_t* arow = &As[BUF][row * LSTRIDE];                                 \
    packA_scatter(arow + i0 * KSLOT, arow + KC, xa0);                         \
    packA_scatter(arow + (i0 + 16) * KSLOT, arow + KC, xa1);                  \
    uint_t p6[6];                                                             \
    packW(&rawc[row][0], i0, us0, rr0, p6);                                   \
    writeT(&Ws[BUF][row * LSTRIDE + i0 * KSLOT], p6);                         \
    packW(&rawc[row][0], i0 + 16, us1, rr1, p6);                              \
    writeT(&Ws[BUF][row * LSTRIDE + (i0 + 16) * KSLOT], p6);                  \
  }

  f32x4 acc = {0.f, 0.f, 0.f, 0.f};

  // prologue: chunk 0
  LOADC(0)
  CVTSTORE
  __syncthreads();
  PACK(0)
  __syncthreads();

  for (int c = 0; c < NCHUNK; ++c) {
    const int cur = c & 1;

    if (c + 1 < NCHUNK) { LOADC(c + 1) }       // issue next chunk's (coalesced) loads
    __builtin_amdgcn_sched_barrier(0);         // keep them issued before MFMA

    // MFMA: wave w owns K-slice [w*96, w*96+96) of current chunk
    __builtin_amdgcn_s_setprio(1);
#pragma unroll
    for (int s = 0; s < 3; ++s) {
      const int k = w * 96 + s * 32 + klane;
      short8 af  = *(const short8*)&As[cur][mn * LSTRIDE + k];
      short8 bfr = *(const short8*)&Ws[cur][mn * LSTRIDE + k];
      acc = __builtin_amdgcn_mfma_f32_16x16x32_bf16(af, bfr, acc, 0, 0, 0);
    }
    __builtin_amdgcn_s_setprio(0);

    if (c + 1 < NCHUNK) {
      CVTSTORE                                 // waits loads; rawc free (read last chunk)
      __syncthreads();                         // rawc visible
      PACK(cur ^ 1)                            // build next chunk into other buffer
    }
    __syncthreads();
  }

  // cross-wave split-K reduce (red overlays the now-dead rawc), then write
  f32x4* red = (f32x4*)&rawc[0][0];
  if (w > 0) red[(w - 1) * 64 + lane] = acc;
  __syncthreads();

  if (w == 0) {
    const f32x4 q0 = red[lane];
    const f32x4 q1 = red[64 + lane];
    const f32x4 q2 = red[128 + lane];
#pragma unroll
    for (int q = 0; q < 4; ++q) acc[q] += q0[q] + q1[q] + q2[q];

    // C/D layout (HW-verified): col = lane&15, row = (lane>>4)*4 + reg
    const int col = o0 + mn;
    const int rbase = b0 + (lane >> 4) * 4;
#pragma unroll
    for (int r = 0; r < 4; ++r) {
      out[(size_t)(rbase + r) * OUT_DIM + col] = acc[r];
    }
  }
}

extern "C" void kernel_launch(void* const* d_in, const int* in_sizes, int n_in,
                              void* d_out, int out_size, void* d_ws, size_t ws_size,
                              hipStream_t stream) {
  const float* x    = (const float*)d_in[0];
  const float* coef = (const float*)d_in[1];
  const float* rw   = (const float*)d_in[2];
  const float* uw   = (const float*)d_in[3];
  float* out = (float*)d_out;

  fused<<<512, 256, 0, stream>>>(x, coef, rw, uw, out);
}

// Round 12
// 19.282 us; speedup vs baseline: 2.0658x; 1.1333x over previous
//
#include <hip/hip_runtime.h>
#include <hip/hip_bf16.h>

typedef unsigned short ushort_t;
typedef unsigned int uint_t;
typedef __attribute__((ext_vector_type(8))) short short8;
typedef __attribute__((ext_vector_type(4))) float f32x4;

#define IN_DIM 256
#define OUT_DIM 256
#define NSPL 11                  // 11 bases
#define KSLOT 12                 // + silu/residual slot
#define CHUNK_I 32               // inputs per K-chunk
#define KC (CHUNK_I * KSLOT)     // 384 K-slots per chunk
#define LSTRIDE (KC + 8)         // 392 ushorts = 784B row stride; slots KC..KC+7 = pad/dump
#define NCHUNK 8
#define RAWF 356                 // raw f32 coef row: 352 floats (176 float2) + 4 pad

__device__ __forceinline__ uint_t pk2(float lo, float hi) {
  __hip_bfloat162 h = __float22bfloat162_rn(make_float2(lo, hi));  // v_cvt_pk_bf16_f32, RNE
  union { __hip_bfloat162 h2; uint_t u; } c; c.h2 = h;
  return c.u;
}

// A-cell: closed-form cubic B-spline; placement via LDS scatter (address path).
// OOB slots redirect to the row's pad region (never read by MFMA).
__device__ __forceinline__ void packA_scatter(ushort_t* cb, ushort_t* dump, float xf) {
  const float t = (xf + 1.75f) * 4.0f;
  const float fJ = floorf(t);
  const int J = (int)fJ;
  const float u = t - fJ;
  const float u2 = u * u, u3 = u2 * u, um = 1.0f - u;
  const float n0 = um * um * um * (1.0f / 6.0f);                        // slot J-3
  const float n1 = 0.5f * u3 - u2 + (4.0f / 6.0f);                      // slot J-2
  const float n2 = -0.5f * u3 + 0.5f * u2 + 0.5f * u + (1.0f / 6.0f);   // slot J-1
  const float n3 = u3 * (1.0f / 6.0f);                                  // slot J
  const float silu = xf / (1.0f + __expf(-xf));

  // zero the 12-slot cell (compiler merges to wide ds_writes)
#pragma unroll
  for (int s = 0; s < 12; ++s) cb[s] = 0;

  const uint_t p01 = pk2(n0, n1);
  const uint_t p23 = pk2(n2, n3);
  const uint_t psl = pk2(silu, silu);

  const int base = J - 3;
  ushort_t* w0 = ((unsigned)(base + 0) <= 10u) ? (cb + base + 0) : (dump + 0);
  ushort_t* w1 = ((unsigned)(base + 1) <= 10u) ? (cb + base + 1) : (dump + 1);
  ushort_t* w2 = ((unsigned)(base + 2) <= 10u) ? (cb + base + 2) : (dump + 2);
  ushort_t* w3 = ((unsigned)(base + 3) <= 10u) ? (cb + base + 3) : (dump + 3);
  *w0 = (ushort_t)p01;
  *w1 = (ushort_t)(p01 >> 16);
  *w2 = (ushort_t)p23;
  *w3 = (ushort_t)(p23 >> 16);
  cb[11] = (ushort_t)psl;
}

// W-cell from f32 LDS row: 11 contiguous floats * us, + r slot -> 6 packed dwords
__device__ __forceinline__ void packW_f32(const float* c, float us, float r, uint_t o6[6]) {
  o6[0] = pk2(us * c[0], us * c[1]);
  o6[1] = pk2(us * c[2], us * c[3]);
  o6[2] = pk2(us * c[4], us * c[5]);
  o6[3] = pk2(us * c[6], us * c[7]);
  o6[4] = pk2(us * c[8], us * c[9]);
  o6[5] = pk2(us * c[10], r);
}

__device__ __forceinline__ void writeT(ushort_t* dst, const uint_t* p) {
  uint_t* d = (uint_t*)dst;
#pragma unroll
  for (int j = 0; j < 6; ++j) d[j] = p[j];
}

// ONE kernel, 512 blocks x 256 threads, zero cross-block sync.
// Per chunk: coalesced float2 coef loads -> raw f32 LDS (rawc, wave-local: writer
// and reader rows coincide per wave -> NO barrier needed) -> pack A (LDS scatter)
// and W (fp32 mul+pk2) into double-buffered MFMA tiles. ONE barrier per chunk.
__global__ __launch_bounds__(256, 2) void fused(const float* __restrict__ x,
                                                const float* __restrict__ coef,
                                                const float* __restrict__ rw,
                                                const float* __restrict__ uw,
                                                float* __restrict__ out) {
  __shared__ __attribute__((aligned(16))) ushort_t As[2][16 * LSTRIDE];
  __shared__ __attribute__((aligned(16))) ushort_t Ws[2][16 * LSTRIDE];
  __shared__ __attribute__((aligned(16))) float rawc[16][RAWF];   // reused as `red` at end

  const int tid = threadIdx.x;
  const int lane = tid & 63;
  const int w = tid >> 6;                          // wave 0..3 = K-slice owner
  const int B = blockIdx.x;
  const int mt = B >> 4;                           // 0..31
  const int nt = ((B & 7) << 1) | ((B >> 3) & 1);  // XCD-aware: XCD r owns N-tiles {2r,2r+1}
  const int b0 = mt * 16, o0 = nt * 16;
  const int mn = lane & 15;
  const int klane = (lane >> 4) * 8;

  const int row = tid >> 4;                        // 0..15: tile row this thread builds (wave = row>>2)
  const int i0 = tid & 15;                         // cells (row,i0), (row,i0+16)

  // staged registers for one chunk
  float2 cf[11];
  float xa0, xa1, us0, us1, rr0, rr1;

#define LOADC(C)                                                              \
  {                                                                           \
    const int ib = (C) * CHUNK_I;                                             \
    xa0 = x[(b0 + row) * IN_DIM + ib + i0];                                   \
    xa1 = x[(b0 + row) * IN_DIM + ib + i0 + 16];                              \
    const int orow = o0 + row;                                                \
    us0 = uw[orow * IN_DIM + ib + i0];                                        \
    us1 = uw[orow * IN_DIM + ib + i0 + 16];                                   \
    rr0 = rw[orow * IN_DIM + ib + i0];                                        \
    rr1 = rw[orow * IN_DIM + ib + i0 + 16];                                   \
    const float2* csrc = (const float2*)(coef + ((size_t)orow * IN_DIM + ib) * NSPL); \
    _Pragma("unroll")                                                         \
    for (int j = 0; j < 11; ++j) cf[j] = csrc[i0 + j * 16];  /* 128B/16 lanes */ \
  }

  // raw f32 store: zero VALU, ds_write_b64; same-wave consumer -> lgkmcnt only
#define CVTSTORE                                                              \
  {                                                                           \
    float2* rrow = (float2*)&rawc[row][0];                                    \
    _Pragma("unroll")                                                         \
    for (int j = 0; j < 11; ++j) rrow[i0 + j * 16] = cf[j];                   \
  }

#define PACK(BUF)                                                             \
  {                                                                           \
    ushort_t* arow = &As[BUF][row * LSTRIDE];                                 \
    packA_scatter(arow + i0 * KSLOT, arow + KC, xa0);                         \
    packA_scatter(arow + (i0 + 16) * KSLOT, arow + KC, xa1);                  \
    uint_t p6[6];                                                             \
    packW_f32(&rawc[row][NSPL * i0], us0, rr0, p6);                           \
    writeT(&Ws[BUF][row * LSTRIDE + i0 * KSLOT], p6);                         \
    packW_f32(&rawc[row][NSPL * (i0 + 16)], us1, rr1, p6);                    \
    writeT(&Ws[BUF][row * LSTRIDE + (i0 + 16) * KSLOT], p6);                  \
  }

  f32x4 acc = {0.f, 0.f, 0.f, 0.f};

  // prologue: chunk 0 (CVTSTORE->PACK is wave-local, no barrier between)
  LOADC(0)
  CVTSTORE
  PACK(0)
  __syncthreads();

  for (int c = 0; c < NCHUNK; ++c) {
    const int cur = c & 1;

    if (c + 1 < NCHUNK) { LOADC(c + 1) }       // issue next chunk's (coalesced) loads
    __builtin_amdgcn_sched_barrier(0);         // keep them issued before MFMA

    // MFMA: wave w owns K-slice [w*96, w*96+96) of current chunk
    __builtin_amdgcn_s_setprio(1);
#pragma unroll
    for (int s = 0; s < 3; ++s) {
      const int k = w * 96 + s * 32 + klane;
      short8 af  = *(const short8*)&As[cur][mn * LSTRIDE + k];
      short8 bfr = *(const short8*)&Ws[cur][mn * LSTRIDE + k];
      acc = __builtin_amdgcn_mfma_f32_16x16x32_bf16(af, bfr, acc, 0, 0, 0);
    }
    __builtin_amdgcn_s_setprio(0);

    if (c + 1 < NCHUNK) {
      CVTSTORE                                 // waits vmcnt; wave-local rawc
      PACK(cur ^ 1)                            // build next chunk into other buffer
    }
    __syncthreads();                           // ONE barrier per chunk
  }

  // cross-wave split-K reduce (red overlays the now-dead rawc), then write
  f32x4* red = (f32x4*)&rawc[0][0];
  if (w > 0) red[(w - 1) * 64 + lane] = acc;
  __syncthreads();

  if (w == 0) {
    const f32x4 q0 = red[lane];
    const f32x4 q1 = red[64 + lane];
    const f32x4 q2 = red[128 + lane];
#pragma unroll
    for (int q = 0; q < 4; ++q) acc[q] += q0[q] + q1[q] + q2[q];

    // C/D layout (HW-verified): col = lane&15, row = (lane>>4)*4 + reg
    const int col = o0 + mn;
    const int rbase = b0 + (lane >> 4) * 4;
#pragma unroll
    for (int r = 0; r < 4; ++r) {
      out[(size_t)(rbase + r) * OUT_DIM + col] = acc[r];
    }
  }
}

extern "C" void kernel_launch(void* const* d_in, const int* in_sizes, int n_in,
                              void* d_out, int out_size, void* d_ws, size_t ws_size,
                              hipStream_t stream) {
  const float* x    = (const float*)d_in[0];
  const float* coef = (const float*)d_in[1];
  const float* rw   = (const float*)d_in[2];
  const float* uw   = (const float*)d_in[3];
  float* out = (float*)d_out;

  fused<<<512, 256, 0, stream>>>(x, coef, rw, uw, out);
}